// Round 1
// baseline (2835.679 us; speedup 1.0000x reference)
//
#include <hip/hip_runtime.h>

#define N_    64
#define HW_   240
#define H1_   120
#define H2_   60
#define C0_   3
#define C1_   32
#define C2_   64
#define C3_   128
#define HEAD_ 1280

// ---------------------------------------------------------------------------
// K1: stem conv 3->32, 3x3 s2 p1, 240->120, fused BN(alpha,beta)+ReLU
// 4 outputs per thread along x; weights (864 f32) in LDS.
// ---------------------------------------------------------------------------
__global__ __launch_bounds__(256) void k1_stem(
    const float* __restrict__ x, const float* __restrict__ w,
    const float* __restrict__ alpha, const float* __restrict__ beta,
    float* __restrict__ h1) {
  __shared__ float wl[C1_ * C0_ * 9];  // 864 floats
  for (int e = threadIdx.x; e < C1_ * C0_ * 9; e += 256) wl[e] = w[e];
  __syncthreads();

  int gid = blockIdx.x * 256 + threadIdx.x;
  const int total = N_ * C1_ * H1_ * 30;  // x-groups of 4
  if (gid >= total) return;
  int xg = gid % 30;
  int y  = (gid / 30) % H1_;
  int c  = (gid / (30 * H1_)) % C1_;
  int n  = gid / (30 * H1_ * C1_);
  int x0 = xg * 4;
  int iy0 = 2 * y - 1, ix0 = 2 * x0 - 1;

  float acc0 = 0.f, acc1 = 0.f, acc2 = 0.f, acc3 = 0.f;
  const float* xn = x + ((long)n * C0_) * HW_ * HW_;
  const float* wc = wl + c * 27;
#pragma unroll
  for (int ic = 0; ic < C0_; ic++) {
    const float* xc = xn + ic * HW_ * HW_;
#pragma unroll
    for (int ky = 0; ky < 3; ky++) {
      int iy = iy0 + ky;
      bool yok = (unsigned)iy < (unsigned)HW_;
      const float* row = xc + iy * HW_;
      float v[9];
#pragma unroll
      for (int j = 0; j < 9; j++) {
        int ix = ix0 + j;
        v[j] = (yok && (unsigned)ix < (unsigned)HW_) ? row[ix] : 0.f;
      }
#pragma unroll
      for (int kx = 0; kx < 3; kx++) {
        float wv = wc[(ic * 3 + ky) * 3 + kx];
        acc0 = fmaf(v[kx],     wv, acc0);
        acc1 = fmaf(v[2 + kx], wv, acc1);
        acc2 = fmaf(v[4 + kx], wv, acc2);
        acc3 = fmaf(v[6 + kx], wv, acc3);
      }
    }
  }
  float a = alpha[c], b = beta[c];
  float4 o;
  o.x = fmaxf(fmaf(acc0, a, b), 0.f);
  o.y = fmaxf(fmaf(acc1, a, b), 0.f);
  o.z = fmaxf(fmaf(acc2, a, b), 0.f);
  o.w = fmaxf(fmaf(acc3, a, b), 0.f);
  float* dst = h1 + (((long)n * C1_ + c) * H1_ + y) * H1_ + x0;
  *(float4*)dst = o;
}

// ---------------------------------------------------------------------------
// K2: conv 32->64, 3x3 s2 p1, 120->60, fused BN+ReLU. One block per (oc,n)
// plane; per-oc weights (288 f32) in LDS; 4 outputs/thread along x.
// ---------------------------------------------------------------------------
__global__ __launch_bounds__(256) void k2_conv(
    const float* __restrict__ h1, const float* __restrict__ w,
    const float* __restrict__ alpha, const float* __restrict__ beta,
    float* __restrict__ h2) {
  __shared__ float wl[C1_ * 9];  // 288 floats for this oc
  int oc = blockIdx.x, n = blockIdx.y;
  for (int e = threadIdx.x; e < C1_ * 9; e += 256) wl[e] = w[oc * C1_ * 9 + e];
  __syncthreads();
  float a = alpha[oc], b = beta[oc];
  const float* h1n = h1 + (long)n * C1_ * H1_ * H1_;
  float* dst_plane = h2 + ((long)n * C2_ + oc) * H2_ * H2_;

  for (int it = 0; it < 4; it++) {
    int g = it * 256 + threadIdx.x;
    if (g >= 900) break;  // 60 rows * 15 x-groups
    int y = g / 15, x0 = (g % 15) * 4;
    int iy0 = 2 * y - 1, ix0 = 2 * x0 - 1;
    float acc0 = 0.f, acc1 = 0.f, acc2 = 0.f, acc3 = 0.f;
    for (int ic = 0; ic < C1_; ic++) {
      const float* xc = h1n + ic * H1_ * H1_;
#pragma unroll
      for (int ky = 0; ky < 3; ky++) {
        int iy = iy0 + ky;
        bool yok = (unsigned)iy < (unsigned)H1_;
        const float* row = xc + iy * H1_;
        float v[9];
#pragma unroll
        for (int j = 0; j < 9; j++) {
          int ix = ix0 + j;
          v[j] = (yok && (unsigned)ix < (unsigned)H1_) ? row[ix] : 0.f;
        }
        const float* wr = wl + (ic * 3 + ky) * 3;
#pragma unroll
        for (int kx = 0; kx < 3; kx++) {
          float wv = wr[kx];
          acc0 = fmaf(v[kx],     wv, acc0);
          acc1 = fmaf(v[2 + kx], wv, acc1);
          acc2 = fmaf(v[4 + kx], wv, acc2);
          acc3 = fmaf(v[6 + kx], wv, acc3);
        }
      }
    }
    float4 o;
    o.x = fmaxf(fmaf(acc0, a, b), 0.f);
    o.y = fmaxf(fmaf(acc1, a, b), 0.f);
    o.z = fmaxf(fmaf(acc2, a, b), 0.f);
    o.w = fmaxf(fmaf(acc3, a, b), 0.f);
    *(float4*)(dst_plane + y * H2_ + x0) = o;
  }
}

// ---------------------------------------------------------------------------
// K3: pointwise 1x1 conv 64->128 + BN + ReLU + GAP-sum, fused (h3 never
// materialized). Block tile: 128 oc x 32 px, k=64. w2 transposed [k][oc] in
// LDS (float4 conflict-free compute reads). Per-pixel ReLU, then LDS
// reduction and one global atomicAdd per (n,oc).
// Grid: (8 chunks, 64 n); chunk c covers 32-px tiles [c*15, min(c*15+15,113)).
// ---------------------------------------------------------------------------
__global__ __launch_bounds__(256) void k3_pw_gap(
    const float* __restrict__ h2, const float* __restrict__ w2,
    const float* __restrict__ alpha, const float* __restrict__ beta,
    float* __restrict__ gap) {
  __shared__ float wl[C2_ * C3_];   // [k][oc] 64x128 = 32 KB
  __shared__ float cols[C2_ * 32];  // [k][px] 64x32  = 8 KB
  __shared__ float gsum[C3_];
  int n = blockIdx.y;
  int chunk = blockIdx.x;
  int t = threadIdx.x;

  // stage w2 transposed: global read coalesced; LDS write conflict is a
  // one-time cost per block (512 blocks total).
#pragma unroll
  for (int i = 0; i < 32; i++) {
    int e = i * 256 + t;           // e = oc*64 + k
    int oc = e >> 6, k = e & 63;
    wl[k * C3_ + oc] = w2[e];
  }
  if (t < C3_) gsum[t] = 0.f;

  int oc0 = (t & 31) * 4;
  int pq  = t >> 5;  // 0..7 -> px0 = pq*4
  float a0 = alpha[oc0], a1 = alpha[oc0 + 1], a2v = alpha[oc0 + 2], a3 = alpha[oc0 + 3];
  float b0 = beta[oc0],  b1 = beta[oc0 + 1],  b2v = beta[oc0 + 2],  b3 = beta[oc0 + 3];
  float s0 = 0.f, s1 = 0.f, s2 = 0.f, s3 = 0.f;
  const float* h2n = h2 + (long)n * C2_ * 3600;

  int tile_end = chunk * 15 + 15;
  if (tile_end > 113) tile_end = 113;
  for (int tile = chunk * 15; tile < tile_end; tile++) {
    int p0 = tile * 32;
    __syncthreads();
#pragma unroll
    for (int i = 0; i < 8; i++) {
      int e = i * 256 + t;
      int k = e >> 5, px = e & 31;
      int p = p0 + px;
      cols[e] = (p < 3600) ? h2n[k * 3600 + p] : 0.f;
    }
    __syncthreads();

    float acc[4][4] = {{0.f}};
    for (int k = 0; k < C2_; k++) {
      float4 wv = *(const float4*)(wl + k * C3_ + oc0);
      float4 cv = *(const float4*)(cols + k * 32 + pq * 4);
      acc[0][0] = fmaf(wv.x, cv.x, acc[0][0]);
      acc[0][1] = fmaf(wv.x, cv.y, acc[0][1]);
      acc[0][2] = fmaf(wv.x, cv.z, acc[0][2]);
      acc[0][3] = fmaf(wv.x, cv.w, acc[0][3]);
      acc[1][0] = fmaf(wv.y, cv.x, acc[1][0]);
      acc[1][1] = fmaf(wv.y, cv.y, acc[1][1]);
      acc[1][2] = fmaf(wv.y, cv.z, acc[1][2]);
      acc[1][3] = fmaf(wv.y, cv.w, acc[1][3]);
      acc[2][0] = fmaf(wv.z, cv.x, acc[2][0]);
      acc[2][1] = fmaf(wv.z, cv.y, acc[2][1]);
      acc[2][2] = fmaf(wv.z, cv.z, acc[2][2]);
      acc[2][3] = fmaf(wv.z, cv.w, acc[2][3]);
      acc[3][0] = fmaf(wv.w, cv.x, acc[3][0]);
      acc[3][1] = fmaf(wv.w, cv.y, acc[3][1]);
      acc[3][2] = fmaf(wv.w, cv.z, acc[3][2]);
      acc[3][3] = fmaf(wv.w, cv.w, acc[3][3]);
    }
    int rem = 3600 - p0;  // valid pixels in this tile (<=32)
#pragma unroll
    for (int j = 0; j < 4; j++) {
      int px = pq * 4 + j;
      if (px < rem) {
        s0 += fmaxf(fmaf(acc[0][j], a0, b0), 0.f);
        s1 += fmaxf(fmaf(acc[1][j], a1, b1), 0.f);
        s2 += fmaxf(fmaf(acc[2][j], a2v, b2v), 0.f);
        s3 += fmaxf(fmaf(acc[3][j], a3, b3), 0.f);
      }
    }
  }
  __syncthreads();
  atomicAdd(&gsum[oc0],     s0);
  atomicAdd(&gsum[oc0 + 1], s1);
  atomicAdd(&gsum[oc0 + 2], s2);
  atomicAdd(&gsum[oc0 + 3], s3);
  __syncthreads();
  if (t < C3_) atomicAdd(&gap[n * C3_ + t], gsum[t]);
}

// ---------------------------------------------------------------------------
// K4: head — gap/3600 @ w_head^T, BN fold + ReLU. Block: (n, 256 oc).
// ---------------------------------------------------------------------------
__global__ __launch_bounds__(256) void k4_head(
    const float* __restrict__ gap, const float* __restrict__ wh,
    const float* __restrict__ alpha, const float* __restrict__ beta,
    float* __restrict__ out) {
  __shared__ float g[C3_];
  int n = blockIdx.y;
  int o = blockIdx.x * 256 + threadIdx.x;
  if (threadIdx.x < C3_)
    g[threadIdx.x] = gap[n * C3_ + threadIdx.x] * (1.f / 3600.f);
  __syncthreads();
  const float* wr = wh + (long)o * C3_;
  float acc = 0.f;
#pragma unroll 8
  for (int c = 0; c < C3_; c += 4) {
    float4 wv = *(const float4*)(wr + c);
    acc = fmaf(wv.x, g[c],     acc);
    acc = fmaf(wv.y, g[c + 1], acc);
    acc = fmaf(wv.z, g[c + 2], acc);
    acc = fmaf(wv.w, g[c + 3], acc);
  }
  out[n * HEAD_ + o] = fmaxf(fmaf(acc, alpha[o], beta[o]), 0.f);
}

// ---------------------------------------------------------------------------
extern "C" void kernel_launch(void* const* d_in, const int* in_sizes, int n_in,
                              void* d_out, int out_size, void* d_ws,
                              size_t ws_size, hipStream_t stream) {
  const float* x      = (const float*)d_in[0];
  const float* w_stem = (const float*)d_in[1];
  const float* a_stem = (const float*)d_in[2];
  const float* b_stem = (const float*)d_in[3];
  const float* w1     = (const float*)d_in[4];
  const float* a1     = (const float*)d_in[5];
  const float* b1     = (const float*)d_in[6];
  const float* w2     = (const float*)d_in[7];
  const float* a2     = (const float*)d_in[8];
  const float* b2     = (const float*)d_in[9];
  const float* wh     = (const float*)d_in[10];
  const float* ah     = (const float*)d_in[11];
  const float* bh     = (const float*)d_in[12];
  float* out = (float*)d_out;

  float* h1  = (float*)d_ws;                                   // 64*32*120*120
  float* h2  = h1 + (size_t)N_ * C1_ * H1_ * H1_;              // 64*64*60*60
  float* gap = h2 + (size_t)N_ * C2_ * H2_ * H2_;              // 64*128

  // gap accumulator must start at zero (ws is poisoned 0xAA each launch)
  hipMemsetAsync(gap, 0, (size_t)N_ * C3_ * sizeof(float), stream);

  {  // K1
    int total = N_ * C1_ * H1_ * 30;
    int blocks = (total + 255) / 256;
    k1_stem<<<blocks, 256, 0, stream>>>(x, w_stem, a_stem, b_stem, h1);
  }
  {  // K2
    dim3 grid(C2_, N_);
    k2_conv<<<grid, 256, 0, stream>>>(h1, w1, a1, b1, h2);
  }
  {  // K3
    dim3 grid(8, N_);
    k3_pw_gap<<<grid, 256, 0, stream>>>(h2, w2, a2, b2, gap);
  }
  {  // K4
    dim3 grid(HEAD_ / 256, N_);
    k4_head<<<grid, 256, 0, stream>>>(gap, wh, ah, bh, out);
  }
}

// Round 2
// 859.762 us; speedup vs baseline: 3.2982x; 3.2982x over previous
//
#include <hip/hip_runtime.h>

#define N_    64
#define HW_   240
#define H1_   120
#define H2_   60
#define C0_   3
#define C1_   32
#define C2_   64
#define C3_   128
#define HEAD_ 1280

// ---------------------------------------------------------------------------
// K1: stem conv 3->32, 3x3 s2 p1, 240->120, fused BN+ReLU.
// Each thread: 8 oc x 4 px. Per (ic,ky): 9 input loads feed 96 FMAs.
// Grid: (row_chunk=15, ocg=4, n=64). 240/256 threads active.
// ---------------------------------------------------------------------------
__global__ __launch_bounds__(256) void k1_stem(
    const float* __restrict__ x, const float* __restrict__ w,
    const float* __restrict__ alpha, const float* __restrict__ beta,
    float* __restrict__ h1) {
  __shared__ float wl[8 * C0_ * 3 * 4];  // [oc][ic][ky][kx pad4] = 288 f
  int ocg = blockIdx.y, n = blockIdx.z;
  int oc0 = ocg * 8;
  for (int e = threadIdx.x; e < 8 * 27; e += 256) {
    int oc = e / 27, rem = e % 27;
    int ic = rem / 9, k9 = rem % 9, ky = k9 / 3, kx = k9 % 3;
    wl[((oc * C0_ + ic) * 3 + ky) * 4 + kx] = w[(oc0 + oc) * 27 + rem];
  }
  __syncthreads();
  int t = threadIdx.x;
  if (t >= 240) return;
  int xg = t % 30, r = t / 30;
  int y = blockIdx.x * 8 + r;          // 15*8 = 120 exact
  int x0 = xg * 4;
  int iy0 = 2 * y - 1, ix0 = 2 * x0 - 1;

  bool xok[9];
#pragma unroll
  for (int j = 0; j < 9; j++) xok[j] = (unsigned)(ix0 + j) < (unsigned)HW_;
  bool yok[3];
#pragma unroll
  for (int ky = 0; ky < 3; ky++) yok[ky] = (unsigned)(iy0 + ky) < (unsigned)HW_;

  float acc[8][4];
#pragma unroll
  for (int o = 0; o < 8; o++)
#pragma unroll
    for (int j = 0; j < 4; j++) acc[o][j] = 0.f;

  const float* xn = x + (long)n * C0_ * HW_ * HW_;
#pragma unroll
  for (int ic = 0; ic < C0_; ic++) {
    const float* xc = xn + ic * HW_ * HW_;
#pragma unroll
    for (int ky = 0; ky < 3; ky++) {
      const float* row = xc + (iy0 + ky) * HW_;
      float v[9];
#pragma unroll
      for (int j = 0; j < 9; j++)
        v[j] = (yok[ky] && xok[j]) ? row[ix0 + j] : 0.f;
#pragma unroll
      for (int oc = 0; oc < 8; oc++) {
        float4 wv = *(const float4*)(wl + ((oc * C0_ + ic) * 3 + ky) * 4);
#pragma unroll
        for (int j = 0; j < 4; j++) {
          acc[oc][j] = fmaf(v[2 * j],     wv.x, acc[oc][j]);
          acc[oc][j] = fmaf(v[2 * j + 1], wv.y, acc[oc][j]);
          acc[oc][j] = fmaf(v[2 * j + 2], wv.z, acc[oc][j]);
        }
      }
    }
  }
#pragma unroll
  for (int oc = 0; oc < 8; oc++) {
    float a = alpha[oc0 + oc], b = beta[oc0 + oc];
    float4 o;
    o.x = fmaxf(fmaf(acc[oc][0], a, b), 0.f);
    o.y = fmaxf(fmaf(acc[oc][1], a, b), 0.f);
    o.z = fmaxf(fmaf(acc[oc][2], a, b), 0.f);
    o.w = fmaxf(fmaf(acc[oc][3], a, b), 0.f);
    *(float4*)(h1 + (((long)n * C1_ + oc0 + oc) * H1_ + y) * H1_ + x0) = o;
  }
}

// ---------------------------------------------------------------------------
// K2: conv 32->64, 3x3 s2 p1, 120->60, fused BN+ReLU.
// Each thread: 8 oc x 4 px; per (ic,ky): 9 loads -> 96 FMAs (1:10.7).
// Grid: (row_chunk=4 x 16 rows, ocg=8, n=64). Weights [8oc][32ic][3][4] LDS.
// ---------------------------------------------------------------------------
__global__ __launch_bounds__(256) void k2_conv(
    const float* __restrict__ h1, const float* __restrict__ w,
    const float* __restrict__ alpha, const float* __restrict__ beta,
    float* __restrict__ h2) {
  __shared__ float wl[8 * C1_ * 3 * 4];  // 3072 f = 12 KB
  int ocg = blockIdx.y, n = blockIdx.z;
  int oc0 = ocg * 8;
  for (int e = threadIdx.x; e < 8 * 288; e += 256) {
    int oc = e / 288, rem = e % 288;
    int ic = rem / 9, k9 = rem % 9, ky = k9 / 3, kx = k9 % 3;
    wl[((oc * C1_ + ic) * 3 + ky) * 4 + kx] = w[(oc0 + oc) * 288 + rem];
  }
  __syncthreads();
  int t = threadIdx.x;
  if (t >= 240) return;
  int xg = t % 15, r = t / 15;
  int y = blockIdx.x * 16 + r;
  if (y >= H2_) return;
  int x0 = xg * 4;
  int iy0 = 2 * y - 1, ix0 = 2 * x0 - 1;

  bool xok[9];
#pragma unroll
  for (int j = 0; j < 9; j++) xok[j] = (unsigned)(ix0 + j) < (unsigned)H1_;
  bool yok[3];
#pragma unroll
  for (int ky = 0; ky < 3; ky++) yok[ky] = (unsigned)(iy0 + ky) < (unsigned)H1_;

  float acc[8][4];
#pragma unroll
  for (int o = 0; o < 8; o++)
#pragma unroll
    for (int j = 0; j < 4; j++) acc[o][j] = 0.f;

  const float* h1n = h1 + (long)n * C1_ * H1_ * H1_;
  for (int ic = 0; ic < C1_; ic++) {
    const float* xc = h1n + ic * H1_ * H1_;
#pragma unroll
    for (int ky = 0; ky < 3; ky++) {
      const float* row = xc + (iy0 + ky) * H1_;
      float v[9];
#pragma unroll
      for (int j = 0; j < 9; j++)
        v[j] = (yok[ky] && xok[j]) ? row[ix0 + j] : 0.f;
#pragma unroll
      for (int oc = 0; oc < 8; oc++) {
        float4 wv = *(const float4*)(wl + ((oc * C1_ + ic) * 3 + ky) * 4);
#pragma unroll
        for (int j = 0; j < 4; j++) {
          acc[oc][j] = fmaf(v[2 * j],     wv.x, acc[oc][j]);
          acc[oc][j] = fmaf(v[2 * j + 1], wv.y, acc[oc][j]);
          acc[oc][j] = fmaf(v[2 * j + 2], wv.z, acc[oc][j]);
        }
      }
    }
  }
#pragma unroll
  for (int oc = 0; oc < 8; oc++) {
    float a = alpha[oc0 + oc], b = beta[oc0 + oc];
    float4 o;
    o.x = fmaxf(fmaf(acc[oc][0], a, b), 0.f);
    o.y = fmaxf(fmaf(acc[oc][1], a, b), 0.f);
    o.z = fmaxf(fmaf(acc[oc][2], a, b), 0.f);
    o.w = fmaxf(fmaf(acc[oc][3], a, b), 0.f);
    *(float4*)(h2 + (((long)n * C2_ + oc0 + oc) * H2_ + y) * H2_ + x0) = o;
  }
}

// ---------------------------------------------------------------------------
// K3: pointwise 1x1 conv 64->128 + BN + ReLU + GAP-sum, fused.
// Block tile: 128 oc x 32 px, k=64. w2 transposed [k][oc] in LDS.
// Grid: (16 chunks x 8 tiles, 64 n).
// ---------------------------------------------------------------------------
__global__ __launch_bounds__(256) void k3_pw_gap(
    const float* __restrict__ h2, const float* __restrict__ w2,
    const float* __restrict__ alpha, const float* __restrict__ beta,
    float* __restrict__ gap) {
  __shared__ float wl[C2_ * C3_];   // [k][oc] 32 KB
  __shared__ float cols[C2_ * 32];  // [k][px] 8 KB
  __shared__ float gsum[C3_];
  int n = blockIdx.y;
  int chunk = blockIdx.x;
  int t = threadIdx.x;

#pragma unroll
  for (int i = 0; i < 32; i++) {
    int e = i * 256 + t;           // e = oc*64 + k
    int oc = e >> 6, k = e & 63;
    wl[k * C3_ + oc] = w2[e];
  }
  if (t < C3_) gsum[t] = 0.f;

  int oc0 = (t & 31) * 4;
  int pq  = t >> 5;
  float a0 = alpha[oc0], a1 = alpha[oc0 + 1], a2v = alpha[oc0 + 2], a3 = alpha[oc0 + 3];
  float b0 = beta[oc0],  b1 = beta[oc0 + 1],  b2v = beta[oc0 + 2],  b3 = beta[oc0 + 3];
  float s0 = 0.f, s1 = 0.f, s2 = 0.f, s3 = 0.f;
  const float* h2n = h2 + (long)n * C2_ * 3600;

  int tile0 = chunk * 8;
  int tile_end = tile0 + 8;
  if (tile_end > 113) tile_end = 113;
  for (int tile = tile0; tile < tile_end; tile++) {
    int p0 = tile * 32;
    __syncthreads();
#pragma unroll
    for (int i = 0; i < 8; i++) {
      int e = i * 256 + t;
      int k = e >> 5, px = e & 31;
      int p = p0 + px;
      cols[e] = (p < 3600) ? h2n[k * 3600 + p] : 0.f;
    }
    __syncthreads();

    float acc[4][4] = {{0.f}};
    for (int k = 0; k < C2_; k++) {
      float4 wv = *(const float4*)(wl + k * C3_ + oc0);
      float4 cv = *(const float4*)(cols + k * 32 + pq * 4);
      acc[0][0] = fmaf(wv.x, cv.x, acc[0][0]);
      acc[0][1] = fmaf(wv.x, cv.y, acc[0][1]);
      acc[0][2] = fmaf(wv.x, cv.z, acc[0][2]);
      acc[0][3] = fmaf(wv.x, cv.w, acc[0][3]);
      acc[1][0] = fmaf(wv.y, cv.x, acc[1][0]);
      acc[1][1] = fmaf(wv.y, cv.y, acc[1][1]);
      acc[1][2] = fmaf(wv.y, cv.z, acc[1][2]);
      acc[1][3] = fmaf(wv.y, cv.w, acc[1][3]);
      acc[2][0] = fmaf(wv.z, cv.x, acc[2][0]);
      acc[2][1] = fmaf(wv.z, cv.y, acc[2][1]);
      acc[2][2] = fmaf(wv.z, cv.z, acc[2][2]);
      acc[2][3] = fmaf(wv.z, cv.w, acc[2][3]);
      acc[3][0] = fmaf(wv.w, cv.x, acc[3][0]);
      acc[3][1] = fmaf(wv.w, cv.y, acc[3][1]);
      acc[3][2] = fmaf(wv.w, cv.z, acc[3][2]);
      acc[3][3] = fmaf(wv.w, cv.w, acc[3][3]);
    }
    int rem = 3600 - p0;
#pragma unroll
    for (int j = 0; j < 4; j++) {
      int px = pq * 4 + j;
      if (px < rem) {
        s0 += fmaxf(fmaf(acc[0][j], a0, b0), 0.f);
        s1 += fmaxf(fmaf(acc[1][j], a1, b1), 0.f);
        s2 += fmaxf(fmaf(acc[2][j], a2v, b2v), 0.f);
        s3 += fmaxf(fmaf(acc[3][j], a3, b3), 0.f);
      }
    }
  }
  __syncthreads();
  atomicAdd(&gsum[oc0],     s0);
  atomicAdd(&gsum[oc0 + 1], s1);
  atomicAdd(&gsum[oc0 + 2], s2);
  atomicAdd(&gsum[oc0 + 3], s3);
  __syncthreads();
  if (t < C3_) atomicAdd(&gap[n * C3_ + t], gsum[t]);
}

// ---------------------------------------------------------------------------
// K4: head — gap/3600 @ w_head^T, BN fold + ReLU.
// ---------------------------------------------------------------------------
__global__ __launch_bounds__(256) void k4_head(
    const float* __restrict__ gap, const float* __restrict__ wh,
    const float* __restrict__ alpha, const float* __restrict__ beta,
    float* __restrict__ out) {
  __shared__ float g[C3_];
  int n = blockIdx.y;
  int o = blockIdx.x * 256 + threadIdx.x;
  if (threadIdx.x < C3_)
    g[threadIdx.x] = gap[n * C3_ + threadIdx.x] * (1.f / 3600.f);
  __syncthreads();
  const float* wr = wh + (long)o * C3_;
  float acc = 0.f;
#pragma unroll 8
  for (int c = 0; c < C3_; c += 4) {
    float4 wv = *(const float4*)(wr + c);
    acc = fmaf(wv.x, g[c],     acc);
    acc = fmaf(wv.y, g[c + 1], acc);
    acc = fmaf(wv.z, g[c + 2], acc);
    acc = fmaf(wv.w, g[c + 3], acc);
  }
  out[n * HEAD_ + o] = fmaxf(fmaf(acc, alpha[o], beta[o]), 0.f);
}

// ---------------------------------------------------------------------------
extern "C" void kernel_launch(void* const* d_in, const int* in_sizes, int n_in,
                              void* d_out, int out_size, void* d_ws,
                              size_t ws_size, hipStream_t stream) {
  const float* x      = (const float*)d_in[0];
  const float* w_stem = (const float*)d_in[1];
  const float* a_stem = (const float*)d_in[2];
  const float* b_stem = (const float*)d_in[3];
  const float* w1     = (const float*)d_in[4];
  const float* a1     = (const float*)d_in[5];
  const float* b1     = (const float*)d_in[6];
  const float* w2     = (const float*)d_in[7];
  const float* a2     = (const float*)d_in[8];
  const float* b2     = (const float*)d_in[9];
  const float* wh     = (const float*)d_in[10];
  const float* ah     = (const float*)d_in[11];
  const float* bh     = (const float*)d_in[12];
  float* out = (float*)d_out;

  float* h1  = (float*)d_ws;                                   // 64*32*120*120
  float* h2  = h1 + (size_t)N_ * C1_ * H1_ * H1_;              // 64*64*60*60
  float* gap = h2 + (size_t)N_ * C2_ * H2_ * H2_;              // 64*128

  hipMemsetAsync(gap, 0, (size_t)N_ * C3_ * sizeof(float), stream);

  {  // K1: 15 row-chunks x 4 oc-groups x 64 n
    dim3 grid(15, 4, N_);
    k1_stem<<<grid, 256, 0, stream>>>(x, w_stem, a_stem, b_stem, h1);
  }
  {  // K2: 4 row-chunks x 8 oc-groups x 64 n
    dim3 grid(4, 8, N_);
    k2_conv<<<grid, 256, 0, stream>>>(h1, w1, a1, b1, h2);
  }
  {  // K3: 16 px-chunks x 64 n
    dim3 grid(16, N_);
    k3_pw_gap<<<grid, 256, 0, stream>>>(h2, w2, a2, b2, gap);
  }
  {  // K4
    dim3 grid(HEAD_ / 256, N_);
    k4_head<<<grid, 256, 0, stream>>>(gap, wh, ah, bh, out);
  }
}

// Round 3
// 439.103 us; speedup vs baseline: 6.4579x; 1.9580x over previous
//
#include <hip/hip_runtime.h>

#define N_    64
#define HW_   240
#define H1_   120
#define H2_   60
#define C0_   3
#define C1_   32
#define C2_   64
#define C3_   128
#define HEAD_ 1280

// ---------------------------------------------------------------------------
// K1: stem conv 3->32, 3x3 s2 p1, 240->120, fused BN+ReLU.
// Each thread: 8 oc x 4 px. Per (ic,ky): 3 vector loads (f1 + f4 + f4) feed
// 96 FMAs. Boundary via clamped address + post-select (rare lanes only).
// Grid: (row_chunk=15, ocg=4, n=64). 240/256 threads active.
// ---------------------------------------------------------------------------
__global__ __launch_bounds__(256) void k1_stem(
    const float* __restrict__ x, const float* __restrict__ w,
    const float* __restrict__ alpha, const float* __restrict__ beta,
    float* __restrict__ h1) {
  __shared__ float wl[8 * C0_ * 3 * 4];  // [oc][ic][ky][kx pad4] = 288 f
  int ocg = blockIdx.y, n = blockIdx.z;
  int oc0 = ocg * 8;
  for (int e = threadIdx.x; e < 8 * 27; e += 256) {
    int oc = e / 27, rem = e % 27;
    int ic = rem / 9, k9 = rem % 9, ky = k9 / 3, kx = k9 % 3;
    wl[((oc * C0_ + ic) * 3 + ky) * 4 + kx] = w[(oc0 + oc) * 27 + rem];
  }
  __syncthreads();
  int t = threadIdx.x;
  if (t >= 240) return;
  int xg = t % 30, r = t / 30;
  int y = blockIdx.x * 8 + r;          // 15*8 = 120 exact
  int x0 = xg * 4;
  int iy0 = 2 * y - 1;
  int xA  = 8 * xg;                    // 16B-aligned window start (v[1])
  int x0m = (xg == 0) ? 0 : (xA - 1);  // clamped scalar addr for v[0]
  bool xg0 = (xg == 0);

  // row offsets, clamped (y-mask zeroes the values later)
  int rofs[3];
  bool yok[3];
#pragma unroll
  for (int ky = 0; ky < 3; ky++) {
    int iy = iy0 + ky;
    yok[ky] = (iy >= 0);               // upper bound never exceeded
    rofs[ky] = (iy < 0 ? 0 : iy) * HW_;
  }

  float acc[8][4];
#pragma unroll
  for (int o = 0; o < 8; o++)
#pragma unroll
    for (int j = 0; j < 4; j++) acc[o][j] = 0.f;

  const float* xn = x + (long)n * C0_ * HW_ * HW_;
#pragma unroll
  for (int ic = 0; ic < C0_; ic++) {
    const float* xc = xn + ic * HW_ * HW_;
#pragma unroll
    for (int ky = 0; ky < 3; ky++) {
      const float* row = xc + rofs[ky];
      float  v0 = row[x0m];
      float4 va = *(const float4*)(row + xA);
      float4 vb = *(const float4*)(row + xA + 4);
      bool ym = yok[ky];
      float v[9];
      v[0] = (ym && !xg0) ? v0 : 0.f;
      v[1] = ym ? va.x : 0.f;  v[2] = ym ? va.y : 0.f;
      v[3] = ym ? va.z : 0.f;  v[4] = ym ? va.w : 0.f;
      v[5] = ym ? vb.x : 0.f;  v[6] = ym ? vb.y : 0.f;
      v[7] = ym ? vb.z : 0.f;  v[8] = ym ? vb.w : 0.f;
#pragma unroll
      for (int oc = 0; oc < 8; oc++) {
        float4 wv = *(const float4*)(wl + ((oc * C0_ + ic) * 3 + ky) * 4);
#pragma unroll
        for (int j = 0; j < 4; j++) {
          acc[oc][j] = fmaf(v[2 * j],     wv.x, acc[oc][j]);
          acc[oc][j] = fmaf(v[2 * j + 1], wv.y, acc[oc][j]);
          acc[oc][j] = fmaf(v[2 * j + 2], wv.z, acc[oc][j]);
        }
      }
    }
  }
#pragma unroll
  for (int oc = 0; oc < 8; oc++) {
    float a = alpha[oc0 + oc], b = beta[oc0 + oc];
    float4 o;
    o.x = fmaxf(fmaf(acc[oc][0], a, b), 0.f);
    o.y = fmaxf(fmaf(acc[oc][1], a, b), 0.f);
    o.z = fmaxf(fmaf(acc[oc][2], a, b), 0.f);
    o.w = fmaxf(fmaf(acc[oc][3], a, b), 0.f);
    *(float4*)(h1 + (((long)n * C1_ + oc0 + oc) * H1_ + y) * H1_ + x0) = o;
  }
}

// ---------------------------------------------------------------------------
// K2: conv 32->64, 3x3 s2 p1, 120->60, fused BN+ReLU.
// Each thread: 8 oc x 4 px; per (ic,ky): 3 vector loads -> 96 FMAs.
// Grid: (row_chunk=4 x 16 rows, ocg=8, n=64). Weights [8oc][32ic][3][4] LDS.
// ---------------------------------------------------------------------------
__global__ __launch_bounds__(256) void k2_conv(
    const float* __restrict__ h1, const float* __restrict__ w,
    const float* __restrict__ alpha, const float* __restrict__ beta,
    float* __restrict__ h2) {
  __shared__ float wl[8 * C1_ * 3 * 4];  // 3072 f = 12 KB
  int ocg = blockIdx.y, n = blockIdx.z;
  int oc0 = ocg * 8;
  for (int e = threadIdx.x; e < 8 * 288; e += 256) {
    int oc = e / 288, rem = e % 288;
    int ic = rem / 9, k9 = rem % 9, ky = k9 / 3, kx = k9 % 3;
    wl[((oc * C1_ + ic) * 3 + ky) * 4 + kx] = w[(oc0 + oc) * 288 + rem];
  }
  __syncthreads();
  int t = threadIdx.x;
  if (t >= 240) return;
  int xg = t % 15, r = t / 15;
  int y = blockIdx.x * 16 + r;
  if (y >= H2_) return;
  int x0 = xg * 4;
  int iy0 = 2 * y - 1;
  int xA  = 8 * xg;
  int x0m = (xg == 0) ? 0 : (xA - 1);
  bool xg0 = (xg == 0);

  int rofs[3];
  bool yok[3];
#pragma unroll
  for (int ky = 0; ky < 3; ky++) {
    int iy = iy0 + ky;
    yok[ky] = (iy >= 0);               // max iy = 119, in range
    rofs[ky] = (iy < 0 ? 0 : iy) * H1_;
  }

  float acc[8][4];
#pragma unroll
  for (int o = 0; o < 8; o++)
#pragma unroll
    for (int j = 0; j < 4; j++) acc[o][j] = 0.f;

  const float* h1n = h1 + (long)n * C1_ * H1_ * H1_;
  for (int ic = 0; ic < C1_; ic++) {
    const float* xc = h1n + ic * H1_ * H1_;
#pragma unroll
    for (int ky = 0; ky < 3; ky++) {
      const float* row = xc + rofs[ky];
      float  v0 = row[x0m];
      float4 va = *(const float4*)(row + xA);
      float4 vb = *(const float4*)(row + xA + 4);
      bool ym = yok[ky];
      float v[9];
      v[0] = (ym && !xg0) ? v0 : 0.f;
      v[1] = ym ? va.x : 0.f;  v[2] = ym ? va.y : 0.f;
      v[3] = ym ? va.z : 0.f;  v[4] = ym ? va.w : 0.f;
      v[5] = ym ? vb.x : 0.f;  v[6] = ym ? vb.y : 0.f;
      v[7] = ym ? vb.z : 0.f;  v[8] = ym ? vb.w : 0.f;
#pragma unroll
      for (int oc = 0; oc < 8; oc++) {
        float4 wv = *(const float4*)(wl + ((oc * C1_ + ic) * 3 + ky) * 4);
#pragma unroll
        for (int j = 0; j < 4; j++) {
          acc[oc][j] = fmaf(v[2 * j],     wv.x, acc[oc][j]);
          acc[oc][j] = fmaf(v[2 * j + 1], wv.y, acc[oc][j]);
          acc[oc][j] = fmaf(v[2 * j + 2], wv.z, acc[oc][j]);
        }
      }
    }
  }
#pragma unroll
  for (int oc = 0; oc < 8; oc++) {
    float a = alpha[oc0 + oc], b = beta[oc0 + oc];
    float4 o;
    o.x = fmaxf(fmaf(acc[oc][0], a, b), 0.f);
    o.y = fmaxf(fmaf(acc[oc][1], a, b), 0.f);
    o.z = fmaxf(fmaf(acc[oc][2], a, b), 0.f);
    o.w = fmaxf(fmaf(acc[oc][3], a, b), 0.f);
    *(float4*)(h2 + (((long)n * C2_ + oc0 + oc) * H2_ + y) * H2_ + x0) = o;
  }
}

// ---------------------------------------------------------------------------
// K3: pointwise 1x1 conv 64->128 + BN + ReLU + GAP-sum, fused.
// Block tile: 128 oc x 32 px, k=64. w2 transposed [k][oc] in LDS.
// Grid: (16 chunks x 8 tiles, 64 n).
// ---------------------------------------------------------------------------
__global__ __launch_bounds__(256) void k3_pw_gap(
    const float* __restrict__ h2, const float* __restrict__ w2,
    const float* __restrict__ alpha, const float* __restrict__ beta,
    float* __restrict__ gap) {
  __shared__ float wl[C2_ * C3_];   // [k][oc] 32 KB
  __shared__ float cols[C2_ * 32];  // [k][px] 8 KB
  __shared__ float gsum[C3_];
  int n = blockIdx.y;
  int chunk = blockIdx.x;
  int t = threadIdx.x;

#pragma unroll
  for (int i = 0; i < 32; i++) {
    int e = i * 256 + t;           // e = oc*64 + k
    int oc = e >> 6, k = e & 63;
    wl[k * C3_ + oc] = w2[e];
  }
  if (t < C3_) gsum[t] = 0.f;

  int oc0 = (t & 31) * 4;
  int pq  = t >> 5;
  float a0 = alpha[oc0], a1 = alpha[oc0 + 1], a2v = alpha[oc0 + 2], a3 = alpha[oc0 + 3];
  float b0 = beta[oc0],  b1 = beta[oc0 + 1],  b2v = beta[oc0 + 2],  b3 = beta[oc0 + 3];
  float s0 = 0.f, s1 = 0.f, s2 = 0.f, s3 = 0.f;
  const float* h2n = h2 + (long)n * C2_ * 3600;

  int tile0 = chunk * 8;
  int tile_end = tile0 + 8;
  if (tile_end > 113) tile_end = 113;
  for (int tile = tile0; tile < tile_end; tile++) {
    int p0 = tile * 32;
    __syncthreads();
#pragma unroll
    for (int i = 0; i < 8; i++) {
      int e = i * 256 + t;
      int k = e >> 5, px = e & 31;
      int p = p0 + px;
      cols[e] = (p < 3600) ? h2n[k * 3600 + p] : 0.f;
    }
    __syncthreads();

    float acc[4][4] = {{0.f}};
    for (int k = 0; k < C2_; k++) {
      float4 wv = *(const float4*)(wl + k * C3_ + oc0);
      float4 cv = *(const float4*)(cols + k * 32 + pq * 4);
      acc[0][0] = fmaf(wv.x, cv.x, acc[0][0]);
      acc[0][1] = fmaf(wv.x, cv.y, acc[0][1]);
      acc[0][2] = fmaf(wv.x, cv.z, acc[0][2]);
      acc[0][3] = fmaf(wv.x, cv.w, acc[0][3]);
      acc[1][0] = fmaf(wv.y, cv.x, acc[1][0]);
      acc[1][1] = fmaf(wv.y, cv.y, acc[1][1]);
      acc[1][2] = fmaf(wv.y, cv.z, acc[1][2]);
      acc[1][3] = fmaf(wv.y, cv.w, acc[1][3]);
      acc[2][0] = fmaf(wv.z, cv.x, acc[2][0]);
      acc[2][1] = fmaf(wv.z, cv.y, acc[2][1]);
      acc[2][2] = fmaf(wv.z, cv.z, acc[2][2]);
      acc[2][3] = fmaf(wv.z, cv.w, acc[2][3]);
      acc[3][0] = fmaf(wv.w, cv.x, acc[3][0]);
      acc[3][1] = fmaf(wv.w, cv.y, acc[3][1]);
      acc[3][2] = fmaf(wv.w, cv.z, acc[3][2]);
      acc[3][3] = fmaf(wv.w, cv.w, acc[3][3]);
    }
    int rem = 3600 - p0;
#pragma unroll
    for (int j = 0; j < 4; j++) {
      int px = pq * 4 + j;
      if (px < rem) {
        s0 += fmaxf(fmaf(acc[0][j], a0, b0), 0.f);
        s1 += fmaxf(fmaf(acc[1][j], a1, b1), 0.f);
        s2 += fmaxf(fmaf(acc[2][j], a2v, b2v), 0.f);
        s3 += fmaxf(fmaf(acc[3][j], a3, b3), 0.f);
      }
    }
  }
  __syncthreads();
  atomicAdd(&gsum[oc0],     s0);
  atomicAdd(&gsum[oc0 + 1], s1);
  atomicAdd(&gsum[oc0 + 2], s2);
  atomicAdd(&gsum[oc0 + 3], s3);
  __syncthreads();
  if (t < C3_) atomicAdd(&gap[n * C3_ + t], gsum[t]);
}

// ---------------------------------------------------------------------------
// K4: head — gap/3600 @ w_head^T, BN fold + ReLU.
// ---------------------------------------------------------------------------
__global__ __launch_bounds__(256) void k4_head(
    const float* __restrict__ gap, const float* __restrict__ wh,
    const float* __restrict__ alpha, const float* __restrict__ beta,
    float* __restrict__ out) {
  __shared__ float g[C3_];
  int n = blockIdx.y;
  int o = blockIdx.x * 256 + threadIdx.x;
  if (threadIdx.x < C3_)
    g[threadIdx.x] = gap[n * C3_ + threadIdx.x] * (1.f / 3600.f);
  __syncthreads();
  const float* wr = wh + (long)o * C3_;
  float acc = 0.f;
#pragma unroll 8
  for (int c = 0; c < C3_; c += 4) {
    float4 wv = *(const float4*)(wr + c);
    acc = fmaf(wv.x, g[c],     acc);
    acc = fmaf(wv.y, g[c + 1], acc);
    acc = fmaf(wv.z, g[c + 2], acc);
    acc = fmaf(wv.w, g[c + 3], acc);
  }
  out[n * HEAD_ + o] = fmaxf(fmaf(acc, alpha[o], beta[o]), 0.f);
}

// ---------------------------------------------------------------------------
extern "C" void kernel_launch(void* const* d_in, const int* in_sizes, int n_in,
                              void* d_out, int out_size, void* d_ws,
                              size_t ws_size, hipStream_t stream) {
  const float* x      = (const float*)d_in[0];
  const float* w_stem = (const float*)d_in[1];
  const float* a_stem = (const float*)d_in[2];
  const float* b_stem = (const float*)d_in[3];
  const float* w1     = (const float*)d_in[4];
  const float* a1     = (const float*)d_in[5];
  const float* b1     = (const float*)d_in[6];
  const float* w2     = (const float*)d_in[7];
  const float* a2     = (const float*)d_in[8];
  const float* b2     = (const float*)d_in[9];
  const float* wh     = (const float*)d_in[10];
  const float* ah     = (const float*)d_in[11];
  const float* bh     = (const float*)d_in[12];
  float* out = (float*)d_out;

  float* h1  = (float*)d_ws;                                   // 64*32*120*120
  float* h2  = h1 + (size_t)N_ * C1_ * H1_ * H1_;              // 64*64*60*60
  float* gap = h2 + (size_t)N_ * C2_ * H2_ * H2_;              // 64*128

  hipMemsetAsync(gap, 0, (size_t)N_ * C3_ * sizeof(float), stream);

  {  // K1: 15 row-chunks x 4 oc-groups x 64 n
    dim3 grid(15, 4, N_);
    k1_stem<<<grid, 256, 0, stream>>>(x, w_stem, a_stem, b_stem, h1);
  }
  {  // K2: 4 row-chunks x 8 oc-groups x 64 n
    dim3 grid(4, 8, N_);
    k2_conv<<<grid, 256, 0, stream>>>(h1, w1, a1, b1, h2);
  }
  {  // K3: 16 px-chunks x 64 n
    dim3 grid(16, N_);
    k3_pw_gap<<<grid, 256, 0, stream>>>(h2, w2, a2, b2, gap);
  }
  {  // K4
    dim3 grid(HEAD_ / 256, N_);
    k4_head<<<grid, 256, 0, stream>>>(gap, wh, ah, bh, out);
  }
}

// Round 4
// 254.308 us; speedup vs baseline: 11.1506x; 1.7267x over previous
//
#include <hip/hip_runtime.h>

#define N_    64
#define HW_   240
#define H1_   120
#define H2_   60
#define C0_   3
#define C1_   32
#define C2_   64
#define C3_   128
#define HEAD_ 1280

typedef unsigned short US;
typedef short bf16x8 __attribute__((ext_vector_type(8)));
typedef float f32x16 __attribute__((ext_vector_type(16)));

__device__ __forceinline__ US f2bf(float f) {
  union { float f; unsigned u; } v; v.f = f;
  unsigned r = v.u + 0x7FFF + ((v.u >> 16) & 1);  // RNE
  return (US)(r >> 16);
}

// h1p padded NHWC: [n][122][122][32] bf16. interior pixel (y,x) -> [y+1][x+1].
#define H1P_ROW   (122 * 32)
#define H1P_IMG   (122 * 122 * 32)

// ---------------------------------------------------------------------------
// K0: prep — zero h1p pad cells; convert w1 -> wt1 [ky][oc][kx*32+ic] bf16;
// convert w2 -> wt2 [oc][ic] bf16.
// ---------------------------------------------------------------------------
#define PADN  15488           // pad elems per n
#define PADT  (64 * PADN)     // 991232
__global__ __launch_bounds__(256) void k0_prep(
    const float* __restrict__ w1, const float* __restrict__ w2,
    US* __restrict__ h1p, US* __restrict__ wt1, US* __restrict__ wt2) {
  int gid = blockIdx.x * 256 + threadIdx.x;
  if (gid < PADT) {
    int n = gid / PADN, q = gid % PADN;
    int y, x, ic;
    if (q < 7808) {            // rows 0 and 121, full width
      y = (q < 3904) ? 0 : 121;
      int r = q % 3904; x = r >> 5; ic = r & 31;
    } else {                   // cols 0 and 121, y 1..120
      int q2 = q - 7808;
      x = (q2 < 3840) ? 0 : 121;
      int r = q2 % 3840; y = 1 + (r >> 5); ic = r & 31;
    }
    h1p[((long)n * 122 + y) * H1P_ROW / 32 * 32 + ((long)y * 0) /*noop*/
        ] = 0;  // placeholder avoided below
  }
  // (rewritten without the placeholder for clarity)
  if (gid < PADT) {
    int n = gid / PADN, q = gid % PADN;
    int y, x, ic;
    if (q < 7808) {
      y = (q < 3904) ? 0 : 121;
      int r = q % 3904; x = r >> 5; ic = r & 31;
    } else {
      int q2 = q - 7808;
      x = (q2 < 3840) ? 0 : 121;
      int r = q2 % 3840; y = 1 + (r >> 5); ic = r & 31;
    }
    h1p[(((long)n * 122 + y) * 122 + x) * 32 + ic] = 0;
  } else if (gid < PADT + 18432) {
    int e = gid - PADT;                       // w1 flat [oc][ic][ky][kx]
    int oc = e / 288, ic = (e / 9) % 32, ky = (e / 3) % 3, kx = e % 3;
    wt1[(ky * 64 + oc) * 96 + kx * 32 + ic] = f2bf(w1[e]);
  } else if (gid < PADT + 18432 + 8192) {
    int e = gid - (PADT + 18432);
    wt2[e] = f2bf(w2[e]);
  }
}

// ---------------------------------------------------------------------------
// K1: stem conv 3->32, 3x3 s2 p1, fused BN+ReLU; f32 vector math, writes
// padded NHWC bf16. Thread: 8 oc x 4 px. Grid (15, 4, 64), 240/256 active.
// ---------------------------------------------------------------------------
__global__ __launch_bounds__(256) void k1_stem(
    const float* __restrict__ x, const float* __restrict__ w,
    const float* __restrict__ alpha, const float* __restrict__ beta,
    US* __restrict__ h1p) {
  __shared__ float wl[8 * C0_ * 3 * 4];
  int ocg = blockIdx.y, n = blockIdx.z;
  int oc0 = ocg * 8;
  for (int e = threadIdx.x; e < 8 * 27; e += 256) {
    int oc = e / 27, rem = e % 27;
    int ic = rem / 9, k9 = rem % 9, ky = k9 / 3, kx = k9 % 3;
    wl[((oc * C0_ + ic) * 3 + ky) * 4 + kx] = w[(oc0 + oc) * 27 + rem];
  }
  __syncthreads();
  int t = threadIdx.x;
  if (t >= 240) return;
  int xg = t % 30, r = t / 30;
  int y = blockIdx.x * 8 + r;
  int x0 = xg * 4;
  int iy0 = 2 * y - 1;
  int xA = 8 * xg;
  int x0m = (xg == 0) ? 0 : (xA - 1);
  bool xg0 = (xg == 0);

  int rofs[3]; bool yok[3];
#pragma unroll
  for (int ky = 0; ky < 3; ky++) {
    int iy = iy0 + ky;
    yok[ky] = (iy >= 0);
    rofs[ky] = (iy < 0 ? 0 : iy) * HW_;
  }

  float acc[8][4];
#pragma unroll
  for (int o = 0; o < 8; o++)
#pragma unroll
    for (int j = 0; j < 4; j++) acc[o][j] = 0.f;

  const float* xn = x + (long)n * C0_ * HW_ * HW_;
#pragma unroll
  for (int ic = 0; ic < C0_; ic++) {
    const float* xc = xn + ic * HW_ * HW_;
#pragma unroll
    for (int ky = 0; ky < 3; ky++) {
      const float* row = xc + rofs[ky];
      float  v0 = row[x0m];
      float4 va = *(const float4*)(row + xA);
      float4 vb = *(const float4*)(row + xA + 4);
      bool ym = yok[ky];
      float v[9];
      v[0] = (ym && !xg0) ? v0 : 0.f;
      v[1] = ym ? va.x : 0.f;  v[2] = ym ? va.y : 0.f;
      v[3] = ym ? va.z : 0.f;  v[4] = ym ? va.w : 0.f;
      v[5] = ym ? vb.x : 0.f;  v[6] = ym ? vb.y : 0.f;
      v[7] = ym ? vb.z : 0.f;  v[8] = ym ? vb.w : 0.f;
#pragma unroll
      for (int oc = 0; oc < 8; oc++) {
        float4 wv = *(const float4*)(wl + ((oc * C0_ + ic) * 3 + ky) * 4);
#pragma unroll
        for (int j = 0; j < 4; j++) {
          acc[oc][j] = fmaf(v[2 * j],     wv.x, acc[oc][j]);
          acc[oc][j] = fmaf(v[2 * j + 1], wv.y, acc[oc][j]);
          acc[oc][j] = fmaf(v[2 * j + 2], wv.z, acc[oc][j]);
        }
      }
    }
  }
  float al[8], bl[8];
#pragma unroll
  for (int o = 0; o < 8; o++) { al[o] = alpha[oc0 + o]; bl[o] = beta[oc0 + o]; }
  long base = (((long)n * 122 + (y + 1)) * 122 + (x0 + 1)) * 32 + oc0;
#pragma unroll
  for (int j = 0; j < 4; j++) {
    unsigned q[4];
#pragma unroll
    for (int k = 0; k < 4; k++) {
      float v0 = fmaxf(fmaf(acc[2 * k][j],     al[2 * k],     bl[2 * k]),     0.f);
      float v1 = fmaxf(fmaf(acc[2 * k + 1][j], al[2 * k + 1], bl[2 * k + 1]), 0.f);
      q[k] = (unsigned)f2bf(v0) | ((unsigned)f2bf(v1) << 16);
    }
    uint4 u; u.x = q[0]; u.y = q[1]; u.z = q[2]; u.w = q[3];
    *(uint4*)(h1p + base + j * 32) = u;
  }
}

// ---------------------------------------------------------------------------
// K2: conv 32->64 3x3 s2 via implicit-GEMM MFMA (bf16 in, f32 acc).
// Block 64px x 64oc, 4 waves (2x2). K = 3 ky-slabs of 96 contiguous (kx,ic).
// A from global h1p (NHWC, padded -> no masks); B from global wt1.
// Grid (57, 64).
// ---------------------------------------------------------------------------
__global__ __launch_bounds__(256) void k2_mfma(
    const US* __restrict__ h1p, const US* __restrict__ wt1,
    const float* __restrict__ alpha, const float* __restrict__ beta,
    US* __restrict__ h2p) {
  int n = blockIdx.y, tile = blockIdx.x;
  int t = threadIdx.x, w = t >> 6, l = t & 63;
  int wm = w & 1, wn = w >> 1;
  int pxb = tile * 64 + wm * 32;
  int lane31 = l & 31, half = l >> 5;
  int p = pxb + lane31; int pc = p < 3600 ? p : 3599;
  int y = pc / 60, xx = pc % 60;
  long abase = (((long)n * 122 + 2 * y) * 122 + 2 * xx) * 32 + half * 8;
  int oc = wn * 32 + lane31;
  const US* bbase = wt1 + oc * 96 + half * 8;

  f32x16 acc;
#pragma unroll
  for (int i = 0; i < 16; i++) acc[i] = 0.f;

#pragma unroll
  for (int ky = 0; ky < 3; ky++) {
    const US* aptr = h1p + abase + ky * H1P_ROW;
    const US* bptr = bbase + ky * (64 * 96);
#pragma unroll
    for (int s = 0; s < 6; s++) {
      bf16x8 av = *(const bf16x8*)(aptr + s * 16);
      bf16x8 bv = *(const bf16x8*)(bptr + s * 16);
      acc = __builtin_amdgcn_mfma_f32_32x32x16_bf16(av, bv, acc, 0, 0, 0);
    }
  }
  float al = alpha[oc], be = beta[oc];
  US* out = h2p + (long)n * 3600 * 64 + oc;
#pragma unroll
  for (int r = 0; r < 16; r++) {
    int row = (r & 3) + 8 * (r >> 2) + 4 * half;
    int pp = pxb + row;
    if (pp < 3600) {
      float v = fmaxf(fmaf(acc[r], al, be), 0.f);
      out[(long)pp * 64] = f2bf(v);
    }
  }
}

// ---------------------------------------------------------------------------
// K3: pointwise 64->128 + BN + ReLU + GAP via MFMA. Wave w owns oc-tile
// 32w..32w+31; loops px tiles of 32; D col = oc (lane-invariant) so per-lane
// scalar running sum; shfl_xor(32) combines row halves; one atomic per oc.
// Grid (8, 64).
// ---------------------------------------------------------------------------
__global__ __launch_bounds__(256) void k3_mfma(
    const US* __restrict__ h2p, const US* __restrict__ wt2,
    const float* __restrict__ alpha, const float* __restrict__ beta,
    float* __restrict__ gap) {
  int n = blockIdx.y, chunk = blockIdx.x;
  int t = threadIdx.x, w = t >> 6, l = t & 63;
  int lane31 = l & 31, half = l >> 5;
  int oc = w * 32 + lane31;
  float al = alpha[oc], be = beta[oc];
  const US* bbase = wt2 + oc * 64 + half * 8;
  int t0 = chunk * 14, t1 = (chunk == 7) ? 113 : (t0 + 14);
  const US* h2n = h2p + (long)n * 3600 * 64;
  float s = 0.f;
  for (int tile = t0; tile < t1; tile++) {
    int p0 = tile * 32;
    int p = p0 + lane31; int pc = p < 3600 ? p : 3599;
    const US* aptr = h2n + (long)pc * 64 + half * 8;
    f32x16 acc;
#pragma unroll
    for (int i = 0; i < 16; i++) acc[i] = 0.f;
#pragma unroll
    for (int s4 = 0; s4 < 4; s4++) {
      bf16x8 av = *(const bf16x8*)(aptr + s4 * 16);
      bf16x8 bv = *(const bf16x8*)(bbase + s4 * 16);
      acc = __builtin_amdgcn_mfma_f32_32x32x16_bf16(av, bv, acc, 0, 0, 0);
    }
    if (p0 + 31 < 3600) {
#pragma unroll
      for (int r = 0; r < 16; r++) s += fmaxf(fmaf(acc[r], al, be), 0.f);
    } else {
#pragma unroll
      for (int r = 0; r < 16; r++) {
        int row = (r & 3) + 8 * (r >> 2) + 4 * half;
        if (p0 + row < 3600) s += fmaxf(fmaf(acc[r], al, be), 0.f);
      }
    }
  }
  s += __shfl_xor(s, 32);
  if (half == 0) atomicAdd(gap + n * C3_ + oc, s);
}

// ---------------------------------------------------------------------------
// K4: head — gap/3600 @ w_head^T, BN fold + ReLU (f32).
// ---------------------------------------------------------------------------
__global__ __launch_bounds__(256) void k4_head(
    const float* __restrict__ gap, const float* __restrict__ wh,
    const float* __restrict__ alpha, const float* __restrict__ beta,
    float* __restrict__ out) {
  __shared__ float g[C3_];
  int n = blockIdx.y;
  int o = blockIdx.x * 256 + threadIdx.x;
  if (threadIdx.x < C3_)
    g[threadIdx.x] = gap[n * C3_ + threadIdx.x] * (1.f / 3600.f);
  __syncthreads();
  const float* wr = wh + (long)o * C3_;
  float acc = 0.f;
#pragma unroll 8
  for (int c = 0; c < C3_; c += 4) {
    float4 wv = *(const float4*)(wr + c);
    acc = fmaf(wv.x, g[c],     acc);
    acc = fmaf(wv.y, g[c + 1], acc);
    acc = fmaf(wv.z, g[c + 2], acc);
    acc = fmaf(wv.w, g[c + 3], acc);
  }
  out[n * HEAD_ + o] = fmaxf(fmaf(acc, alpha[o], beta[o]), 0.f);
}

// ---------------------------------------------------------------------------
extern "C" void kernel_launch(void* const* d_in, const int* in_sizes, int n_in,
                              void* d_out, int out_size, void* d_ws,
                              size_t ws_size, hipStream_t stream) {
  const float* x      = (const float*)d_in[0];
  const float* w_stem = (const float*)d_in[1];
  const float* a_stem = (const float*)d_in[2];
  const float* b_stem = (const float*)d_in[3];
  const float* w1     = (const float*)d_in[4];
  const float* a1     = (const float*)d_in[5];
  const float* b1     = (const float*)d_in[6];
  const float* w2     = (const float*)d_in[7];
  const float* a2     = (const float*)d_in[8];
  const float* b2     = (const float*)d_in[9];
  const float* wh     = (const float*)d_in[10];
  const float* ah     = (const float*)d_in[11];
  const float* bh     = (const float*)d_in[12];
  float* out = (float*)d_out;

  US* h1p = (US*)d_ws;                                   // 64*122*122*32
  US* h2p = h1p + (size_t)N_ * 122 * 122 * 32;           // 64*3600*64
  US* wt1 = h2p + (size_t)N_ * 3600 * 64;                // 3*64*96
  US* wt2 = wt1 + 3 * 64 * 96;                           // 128*64
  float* gap = (float*)(wt2 + C3_ * C2_);                // 64*128 f32

  hipMemsetAsync(gap, 0, (size_t)N_ * C3_ * sizeof(float), stream);

  {  // K0 prep: pad-zero + weight conversion
    int total = PADT + 18432 + 8192;
    k0_prep<<<(total + 255) / 256, 256, 0, stream>>>(w1, w2, h1p, wt1, wt2);
  }
  {  // K1
    dim3 grid(15, 4, N_);
    k1_stem<<<grid, 256, 0, stream>>>(x, w_stem, a_stem, b_stem, h1p);
  }
  {  // K2
    dim3 grid(57, N_);
    k2_mfma<<<grid, 256, 0, stream>>>(h1p, wt1, a1, b1, h2p);
  }
  {  // K3
    dim3 grid(8, N_);
    k3_mfma<<<grid, 256, 0, stream>>>(h2p, wt2, a2, b2, gap);
  }
  {  // K4
    dim3 grid(HEAD_ / 256, N_);
    k4_head<<<grid, 256, 0, stream>>>(gap, wh, ah, bh, out);
  }
}

// Round 5
// 232.315 us; speedup vs baseline: 12.2062x; 1.0947x over previous
//
#include <hip/hip_runtime.h>

#define N_    64
#define HW_   240
#define H1_   120
#define H2_   60
#define C0_   3
#define C1_   32
#define C2_   64
#define C3_   128
#define HEAD_ 1280

typedef unsigned short US;
typedef short bf16x8 __attribute__((ext_vector_type(8)));
typedef float f32x16 __attribute__((ext_vector_type(16)));

__device__ __forceinline__ US f2bf(float f) {
  union { float f; unsigned u; } v; v.f = f;
  unsigned r = v.u + 0x7FFF + ((v.u >> 16) & 1);  // RNE
  return (US)(r >> 16);
}

// h1p padded NHWC: [n][122][122][32] bf16. interior pixel (y,x) -> [y+1][x+1].
#define H1P_ROW   (122 * 32)

// ---------------------------------------------------------------------------
// K0: prep — zero h1p pad cells; convert w1 -> wt1 [ky][oc][kx*32+ic] bf16;
// convert w2 -> wt2 [oc][ic] bf16.
// ---------------------------------------------------------------------------
#define PADN  15488           // pad elems per n
#define PADT  (64 * PADN)     // 991232
__global__ __launch_bounds__(256) void k0_prep(
    const float* __restrict__ w1, const float* __restrict__ w2,
    US* __restrict__ h1p, US* __restrict__ wt1, US* __restrict__ wt2) {
  int gid = blockIdx.x * 256 + threadIdx.x;
  if (gid < PADT) {
    int n = gid / PADN, q = gid % PADN;
    int y, x, ic;
    if (q < 7808) {            // rows 0 and 121, full width
      y = (q < 3904) ? 0 : 121;
      int r = q % 3904; x = r >> 5; ic = r & 31;
    } else {                   // cols 0 and 121, y 1..120
      int q2 = q - 7808;
      x = (q2 < 3840) ? 0 : 121;
      int r = q2 % 3840; y = 1 + (r >> 5); ic = r & 31;
    }
    h1p[(((long)n * 122 + y) * 122 + x) * 32 + ic] = 0;
  } else if (gid < PADT + 18432) {
    int e = gid - PADT;                       // w1 flat [oc][ic][ky][kx]
    int oc = e / 288, ic = (e / 9) % 32, ky = (e / 3) % 3, kx = e % 3;
    wt1[(ky * 64 + oc) * 96 + kx * 32 + ic] = f2bf(w1[e]);
  } else if (gid < PADT + 18432 + 8192) {
    int e = gid - (PADT + 18432);
    wt2[e] = f2bf(w2[e]);
  }
}

// ---------------------------------------------------------------------------
// K1: stem conv 3->32, 3x3 s2 p1, fused BN+ReLU; f32 vector math, writes
// padded NHWC bf16. Thread: 32 oc x 4 px -> each thread stores 4 full 64-B
// pixel chunks contiguously (no partial-cache-line RMW).
// Grid (15, 64), 240/256 threads active.
// ---------------------------------------------------------------------------
__global__ __launch_bounds__(256) void k1_stem(
    const float* __restrict__ x, const float* __restrict__ w,
    const float* __restrict__ alpha, const float* __restrict__ beta,
    US* __restrict__ h1p) {
  __shared__ float wl[C1_ * C0_ * 3 * 4];  // [oc][ic][ky][kx pad4] 1152 f
  int n = blockIdx.y;
  for (int e = threadIdx.x; e < C1_ * 27; e += 256) {
    int oc = e / 27, rem = e % 27;
    int ic = rem / 9, ky = (rem / 3) % 3, kx = rem % 3;
    wl[((oc * C0_ + ic) * 3 + ky) * 4 + kx] = w[e];
  }
  __syncthreads();
  int t = threadIdx.x;
  if (t >= 240) return;
  int xg = t % 30, r = t / 30;
  int y = blockIdx.x * 8 + r;          // 15*8 = 120 exact
  int x0 = xg * 4;
  int iy0 = 2 * y - 1;
  int xA = 8 * xg;                     // 16B-aligned window start (v[1])
  int x0m = (xg == 0) ? 0 : (xA - 1);  // clamped scalar addr for v[0]
  bool xg0 = (xg == 0);

  int rofs[3]; bool yok[3];
#pragma unroll
  for (int ky = 0; ky < 3; ky++) {
    int iy = iy0 + ky;
    yok[ky] = (iy >= 0);               // upper bound never exceeded
    rofs[ky] = (iy < 0 ? 0 : iy) * HW_;
  }

  float acc[C1_][4];
#pragma unroll
  for (int o = 0; o < C1_; o++)
#pragma unroll
    for (int j = 0; j < 4; j++) acc[o][j] = 0.f;

  const float* xn = x + (long)n * C0_ * HW_ * HW_;
#pragma unroll
  for (int ic = 0; ic < C0_; ic++) {
    const float* xc = xn + ic * HW_ * HW_;
#pragma unroll
    for (int ky = 0; ky < 3; ky++) {
      const float* row = xc + rofs[ky];
      float  v0 = row[x0m];
      float4 va = *(const float4*)(row + xA);
      float4 vb = *(const float4*)(row + xA + 4);
      bool ym = yok[ky];
      float v[9];
      v[0] = (ym && !xg0) ? v0 : 0.f;
      v[1] = ym ? va.x : 0.f;  v[2] = ym ? va.y : 0.f;
      v[3] = ym ? va.z : 0.f;  v[4] = ym ? va.w : 0.f;
      v[5] = ym ? vb.x : 0.f;  v[6] = ym ? vb.y : 0.f;
      v[7] = ym ? vb.z : 0.f;  v[8] = ym ? vb.w : 0.f;
#pragma unroll
      for (int oc = 0; oc < C1_; oc++) {
        float4 wv = *(const float4*)(wl + ((oc * C0_ + ic) * 3 + ky) * 4);
#pragma unroll
        for (int j = 0; j < 4; j++) {
          acc[oc][j] = fmaf(v[2 * j],     wv.x, acc[oc][j]);
          acc[oc][j] = fmaf(v[2 * j + 1], wv.y, acc[oc][j]);
          acc[oc][j] = fmaf(v[2 * j + 2], wv.z, acc[oc][j]);
        }
      }
    }
  }
  long base = (((long)n * 122 + (y + 1)) * 122 + (x0 + 1)) * 32;
#pragma unroll
  for (int j = 0; j < 4; j++) {        // pixel
#pragma unroll
    for (int g = 0; g < 4; g++) {      // 8-channel group
      unsigned q[4];
#pragma unroll
      for (int k = 0; k < 4; k++) {
        int o = g * 8 + 2 * k;
        float v0 = fmaxf(fmaf(acc[o][j],     alpha[o],     beta[o]),     0.f);
        float v1 = fmaxf(fmaf(acc[o + 1][j], alpha[o + 1], beta[o + 1]), 0.f);
        q[k] = (unsigned)f2bf(v0) | ((unsigned)f2bf(v1) << 16);
      }
      uint4 u; u.x = q[0]; u.y = q[1]; u.z = q[2]; u.w = q[3];
      *(uint4*)(h1p + base + j * 32 + g * 8) = u;
    }
  }
}

// ---------------------------------------------------------------------------
// K2: conv 32->64 3x3 s2 via implicit-GEMM MFMA (bf16 in, f32 acc).
// Block 64px x 64oc, 4 waves (2x2). K = 3 ky-slabs of 96 contiguous (kx,ic).
// A from global h1p (NHWC, padded -> no masks); B from global wt1.
// Grid (57, 64).
// ---------------------------------------------------------------------------
__global__ __launch_bounds__(256) void k2_mfma(
    const US* __restrict__ h1p, const US* __restrict__ wt1,
    const float* __restrict__ alpha, const float* __restrict__ beta,
    US* __restrict__ h2p) {
  int n = blockIdx.y, tile = blockIdx.x;
  int t = threadIdx.x, w = t >> 6, l = t & 63;
  int wm = w & 1, wn = w >> 1;
  int pxb = tile * 64 + wm * 32;
  int lane31 = l & 31, half = l >> 5;
  int p = pxb + lane31; int pc = p < 3600 ? p : 3599;
  int y = pc / 60, xx = pc % 60;
  long abase = (((long)n * 122 + 2 * y) * 122 + 2 * xx) * 32 + half * 8;
  int oc = wn * 32 + lane31;
  const US* bbase = wt1 + oc * 96 + half * 8;

  f32x16 acc;
#pragma unroll
  for (int i = 0; i < 16; i++) acc[i] = 0.f;

#pragma unroll
  for (int ky = 0; ky < 3; ky++) {
    const US* aptr = h1p + abase + ky * H1P_ROW;
    const US* bptr = bbase + ky * (64 * 96);
#pragma unroll
    for (int s = 0; s < 6; s++) {
      bf16x8 av = *(const bf16x8*)(aptr + s * 16);
      bf16x8 bv = *(const bf16x8*)(bptr + s * 16);
      acc = __builtin_amdgcn_mfma_f32_32x32x16_bf16(av, bv, acc, 0, 0, 0);
    }
  }
  float al = alpha[oc], be = beta[oc];
  US* out = h2p + (long)n * 3600 * 64 + oc;
#pragma unroll
  for (int r = 0; r < 16; r++) {
    int row = (r & 3) + 8 * (r >> 2) + 4 * half;
    int pp = pxb + row;
    if (pp < 3600) {
      float v = fmaxf(fmaf(acc[r], al, be), 0.f);
      out[(long)pp * 64] = f2bf(v);
    }
  }
}

// ---------------------------------------------------------------------------
// K3: pointwise 64->128 + BN + ReLU + GAP via MFMA. Wave w owns oc-tile
// 32w..32w+31; loops px tiles of 32; D col = oc (lane-invariant) so per-lane
// scalar running sum; shfl_xor(32) combines row halves; one atomic per oc.
// Grid (8, 64).
// ---------------------------------------------------------------------------
__global__ __launch_bounds__(256) void k3_mfma(
    const US* __restrict__ h2p, const US* __restrict__ wt2,
    const float* __restrict__ alpha, const float* __restrict__ beta,
    float* __restrict__ gap) {
  int n = blockIdx.y, chunk = blockIdx.x;
  int t = threadIdx.x, w = t >> 6, l = t & 63;
  int lane31 = l & 31, half = l >> 5;
  int oc = w * 32 + lane31;
  float al = alpha[oc], be = beta[oc];
  const US* bbase = wt2 + oc * 64 + half * 8;
  int t0 = chunk * 14, t1 = (chunk == 7) ? 113 : (t0 + 14);
  const US* h2n = h2p + (long)n * 3600 * 64;
  float s = 0.f;
  for (int tile = t0; tile < t1; tile++) {
    int p0 = tile * 32;
    int p = p0 + lane31; int pc = p < 3600 ? p : 3599;
    const US* aptr = h2n + (long)pc * 64 + half * 8;
    f32x16 acc;
#pragma unroll
    for (int i = 0; i < 16; i++) acc[i] = 0.f;
#pragma unroll
    for (int s4 = 0; s4 < 4; s4++) {
      bf16x8 av = *(const bf16x8*)(aptr + s4 * 16);
      bf16x8 bv = *(const bf16x8*)(bbase + s4 * 16);
      acc = __builtin_amdgcn_mfma_f32_32x32x16_bf16(av, bv, acc, 0, 0, 0);
    }
    if (p0 + 31 < 3600) {
#pragma unroll
      for (int r = 0; r < 16; r++) s += fmaxf(fmaf(acc[r], al, be), 0.f);
    } else {
#pragma unroll
      for (int r = 0; r < 16; r++) {
        int row = (r & 3) + 8 * (r >> 2) + 4 * half;
        if (p0 + row < 3600) s += fmaxf(fmaf(acc[r], al, be), 0.f);
      }
    }
  }
  s += __shfl_xor(s, 32);
  if (half == 0) atomicAdd(gap + n * C3_ + oc, s);
}

// ---------------------------------------------------------------------------
// K4: head — gap/3600 @ w_head^T, BN fold + ReLU (f32).
// ---------------------------------------------------------------------------
__global__ __launch_bounds__(256) void k4_head(
    const float* __restrict__ gap, const float* __restrict__ wh,
    const float* __restrict__ alpha, const float* __restrict__ beta,
    float* __restrict__ out) {
  __shared__ float g[C3_];
  int n = blockIdx.y;
  int o = blockIdx.x * 256 + threadIdx.x;
  if (threadIdx.x < C3_)
    g[threadIdx.x] = gap[n * C3_ + threadIdx.x] * (1.f / 3600.f);
  __syncthreads();
  const float* wr = wh + (long)o * C3_;
  float acc = 0.f;
#pragma unroll 8
  for (int c = 0; c < C3_; c += 4) {
    float4 wv = *(const float4*)(wr + c);
    acc = fmaf(wv.x, g[c],     acc);
    acc = fmaf(wv.y, g[c + 1], acc);
    acc = fmaf(wv.z, g[c + 2], acc);
    acc = fmaf(wv.w, g[c + 3], acc);
  }
  out[n * HEAD_ + o] = fmaxf(fmaf(acc, alpha[o], beta[o]), 0.f);
}

// ---------------------------------------------------------------------------
extern "C" void kernel_launch(void* const* d_in, const int* in_sizes, int n_in,
                              void* d_out, int out_size, void* d_ws,
                              size_t ws_size, hipStream_t stream) {
  const float* x      = (const float*)d_in[0];
  const float* w_stem = (const float*)d_in[1];
  const float* a_stem = (const float*)d_in[2];
  const float* b_stem = (const float*)d_in[3];
  const float* w1     = (const float*)d_in[4];
  const float* a1     = (const float*)d_in[5];
  const float* b1     = (const float*)d_in[6];
  const float* w2     = (const float*)d_in[7];
  const float* a2     = (const float*)d_in[8];
  const float* b2     = (const float*)d_in[9];
  const float* wh     = (const float*)d_in[10];
  const float* ah     = (const float*)d_in[11];
  const float* bh     = (const float*)d_in[12];
  float* out = (float*)d_out;

  US* h1p = (US*)d_ws;                                   // 64*122*122*32
  US* h2p = h1p + (size_t)N_ * 122 * 122 * 32;           // 64*3600*64
  US* wt1 = h2p + (size_t)N_ * 3600 * 64;                // 3*64*96
  US* wt2 = wt1 + 3 * 64 * 96;                           // 128*64
  float* gap = (float*)(wt2 + C3_ * C2_);                // 64*128 f32

  hipMemsetAsync(gap, 0, (size_t)N_ * C3_ * sizeof(float), stream);

  {  // K0 prep: pad-zero + weight conversion
    int total = PADT + 18432 + 8192;
    k0_prep<<<(total + 255) / 256, 256, 0, stream>>>(w1, w2, h1p, wt1, wt2);
  }
  {  // K1: 15 row-chunks x 64 n
    dim3 grid(15, N_);
    k1_stem<<<grid, 256, 0, stream>>>(x, w_stem, a_stem, b_stem, h1p);
  }
  {  // K2
    dim3 grid(57, N_);
    k2_mfma<<<grid, 256, 0, stream>>>(h1p, wt1, a1, b1, h2p);
  }
  {  // K3
    dim3 grid(8, N_);
    k3_mfma<<<grid, 256, 0, stream>>>(h2p, wt2, a2, b2, gap);
  }
  {  // K4
    dim3 grid(HEAD_ / 256, N_);
    k4_head<<<grid, 256, 0, stream>>>(gap, wh, ah, bh, out);
  }
}